// Round 5
// baseline (691.326 us; speedup 1.0000x reference)
//
#include <hip/hip_runtime.h>

typedef unsigned short ushort_t;
typedef __attribute__((ext_vector_type(8))) short   short8_t;
typedef __attribute__((ext_vector_type(4))) float   float4_t;
typedef __attribute__((ext_vector_type(4))) unsigned short ushort4_t;

__device__ __forceinline__ ushort_t f2b(float f) {
    unsigned int u = __float_as_uint(f);
    u += 0x7FFFu + ((u >> 16) & 1u);      // round-to-nearest-even
    return (ushort_t)(u >> 16);
}
__device__ __forceinline__ float b2f(ushort_t s) {
    return __uint_as_float(((unsigned int)s) << 16);
}
__device__ __forceinline__ float frcp(float x) { return __builtin_amdgcn_rcpf(x); }
__device__ __forceinline__ float sigf(float x) { return frcp(1.f + __expf(-x)); }
__device__ __forceinline__ float tanhf_fast(float x) {
    return 1.f - 2.f * frcp(__expf(2.f * x) + 1.f);
}

// ---------------- weight convert: fp32 -> bf16 fragment-order ----------------
// Round-2 proven version (passed harness): one thread produces one 8-ushort
// lane-fragment (2x float4 read, 16B contiguous store). Layout identical to
// original: rec frags ((m*16+tn)*8+kf)*512 + lane*8 + j at [0,196608);
// in frags ((m*16+tn)*6+kf)*512 + lane*8 + j at [196608,344064).
__global__ void cvt_w(const float* __restrict__ ffr, const float* __restrict__ gr,
                      const float* __restrict__ tr,  const float* __restrict__ ffi,
                      const float* __restrict__ gi,  const float* __restrict__ ti,
                      ushort_t* __restrict__ o)
{
    int f = blockIdx.x * 256 + threadIdx.x;   // [0, 43008) = 344064/8
    const float* W;
    int src;
    if (f < 24576) {                           // rec frags
        int lane = f & 63;
        int kf   = (f >> 6) & 7;
        int tn   = (f >> 9) & 15;
        int m    = f >> 13;
        int col  = tn*16 + (lane & 15);
        int k0   = kf*32 + (lane >> 4)*8;
        W = (m == 0) ? ffr : (m == 1) ? gr : tr;
        src = (col << 8) + k0;
    } else {                                   // in frags
        int g    = f - 24576;
        int lane = g & 63;
        int q    = g >> 6;                     // (m*16+tn)*6+kf
        int kf   = q % 6;
        int tt   = q / 6;
        int tn   = tt & 15;
        int m    = tt >> 4;
        int col  = tn*16 + (lane & 15);
        int k0   = kf*32 + (lane >> 4)*8;
        W = (m == 0) ? ffi : (m == 1) ? gi : ti;
        src = col*192 + k0;
    }
    const float4_t v0 = *(const float4_t*)(W + src);
    const float4_t v1 = *(const float4_t*)(W + src + 4);
    ushort4_t a, b;
    a.x = f2b(v0.x); a.y = f2b(v0.y); a.z = f2b(v0.z); a.w = f2b(v0.w);
    b.x = f2b(v1.x); b.y = f2b(v1.y); b.z = f2b(v1.z); b.w = f2b(v1.w);
    *(ushort4_t*)(o + (f << 3))     = a;
    *(ushort4_t*)(o + (f << 3) + 4) = b;
}

// ---------------- fused LTC kernel ----------------
// MEASUREMENT BUILD: round-0 proven structure verbatim, with the input
// projection phase executed TWICE per chunk (rep loop). Rep 1 recomputes and
// rewrites byte-identical values to the wave-private Pl slots; the asm
// memory clobber between reps prevents load-CSE / dead-store elimination so
// the second rep pays the full marginal cost (global B-frag loads included).
// Purpose: dispatch_dur - 401us == true proj-phase cost. Correctness is
// unchanged (deterministic recompute; Al is stable during proj: staging
// writes happen only after the step-0 barrier which gates on all waves
// finishing both reps).
__global__ __launch_bounds__(512, 2) void ltc_fused(
    const float* __restrict__ x,
    const ushort_t* __restrict__ wbf,
    const float* __restrict__ ff_in_b, const float* __restrict__ ff_bias,
    const float* __restrict__ g_in_b,  const float* __restrict__ g_bias,
    const float* __restrict__ t_in_b,  const float* __restrict__ t_bias,
    const float* __restrict__ head_w,  const float* __restrict__ head_b,
    float* __restrict__ out)
{
    __shared__ __align__(16) ushort_t smem[70400];
    ushort_t* Al = smem;                 // 12800 el
    ushort_t* Pl = smem + 12800;         // 49152 el
    ushort_t* Hb = smem + 61952;         // 8448 el = 2 x 4224

    const int tid   = threadIdx.x;
    const int lane  = tid & 63;
    const int wv    = tid >> 6;
    const int l16   = lane & 15;
    const int l4    = lane >> 4;
    const int bbase = blockIdx.x << 4;

    const ushort_t* recF = wbf;
    const ushort_t* inF  = wbf + 196608;

    const int tn0  = 2*wv;
    const int tn1  = 2*wv + 1;
    const int col0 = 32*wv + l16;        // n=0 col (for bias/epilogue)
    const int col1 = col0 + 16;          // n=1 col

    // resident rec-weight B-fragments, coalesced loads (base + lane*16B)
    short8_t wr01[2][2][8];              // m=0,1 : 128 regs
    short8_t wr2[2][4];                  // m=2, kf 0..3 : 32 regs
#pragma unroll
    for (int m = 0; m < 2; ++m)
#pragma unroll
        for (int n = 0; n < 2; ++n) {
            const int tn = n ? tn1 : tn0;
#pragma unroll
            for (int k = 0; k < 8; ++k)
                wr01[m][n][k] = *(const short8_t*)(
                    recF + (((m*16 + tn)*8 + k) << 9) + lane*8);
        }
#pragma unroll
    for (int n = 0; n < 2; ++n) {
        const int tn = n ? tn1 : tn0;
#pragma unroll
        for (int k = 0; k < 4; ++k)
            wr2[n][k] = *(const short8_t*)(
                recF + (((32 + tn)*8 + k) << 9) + lane*8);
    }

    float hp[2][4];
#pragma unroll
    for (int n = 0; n < 2; ++n)
#pragma unroll
        for (int r = 0; r < 4; ++r) hp[n][r] = 0.f;

    for (int i = tid; i < 4224; i += 512) Hb[i] = 0;   // h0 = 0 (buffer 0)

    // stage chunk 0 into Al
#pragma unroll 1
    for (int p = 0; p < 6; ++p) {
        int flat = p*512 + tid;               // [0,3072) float4s
        int w4   = flat & 15;
        int tt   = (flat >> 4) & 3;
        int rest = flat >> 6;                 // b*3 + c
        int c = rest % 3;
        int b = rest / 3;
        const float4_t v = *(const float4_t*)(
            x + (((bbase + b)*3 + c)*4096) + tt*64 + (w4 << 2));
        ushort4_t o;
        o.x = f2b(v.x); o.y = f2b(v.y); o.z = f2b(v.z); o.w = f2b(v.w);
        *(ushort4_t*)(Al + tt*3200 + b*200 + (c << 6) + (w4 << 2)) = o;
    }
    __syncthreads();

#pragma unroll 1
    for (int tc = 0; tc < 16; ++tc) {
        // ======== input projection, EXECUTED TWICE (ablation measurement)
#pragma unroll 1
        for (int rep = 0; rep < 2; ++rep) {
#pragma unroll 1
            for (int n = 0; n < 2; ++n) {
                const int tn  = n ? tn1 : tn0;
                const int col = n ? col1 : col0;
                float bs[3];
                bs[0] = ff_in_b[col] + ff_bias[col];
                bs[1] = g_in_b[col]  + g_bias[col];
                bs[2] = t_in_b[col]  + t_bias[col];
                float4_t pac[3][4];
#pragma unroll
                for (int m = 0; m < 3; ++m)
#pragma unroll
                    for (int t = 0; t < 4; ++t)
                        pac[m][t] = (float4_t){bs[m], bs[m], bs[m], bs[m]};
                const ushort_t* wcb = inF + lane*8;
#pragma unroll
                for (int kf = 0; kf < 6; ++kf) {
                    const short8_t bk0 = *(const short8_t*)(wcb + (((     tn)*6 + kf) << 9));
                    const short8_t bk1 = *(const short8_t*)(wcb + (((16 + tn)*6 + kf) << 9));
                    const short8_t bk2 = *(const short8_t*)(wcb + (((32 + tn)*6 + kf) << 9));
#pragma unroll
                    for (int t = 0; t < 4; ++t) {
                        const short8_t a = *(const short8_t*)(
                            Al + t*3200 + l16*200 + kf*32 + l4*8);
                        pac[0][t] = __builtin_amdgcn_mfma_f32_16x16x32_bf16(a, bk0, pac[0][t], 0, 0, 0);
                        pac[1][t] = __builtin_amdgcn_mfma_f32_16x16x32_bf16(a, bk1, pac[1][t], 0, 0, 0);
                        pac[2][t] = __builtin_amdgcn_mfma_f32_16x16x32_bf16(a, bk2, pac[2][t], 0, 0, 0);
                    }
                }
#pragma unroll
                for (int m = 0; m < 3; ++m)
#pragma unroll
                    for (int t = 0; t < 4; ++t) {
                        ushort4_t o;
                        o.x = f2b(pac[m][t].x); o.y = f2b(pac[m][t].y);
                        o.z = f2b(pac[m][t].z); o.w = f2b(pac[m][t].w);
                        *(ushort4_t*)(Pl + ((((t*8 + wv)*3 + m)*2 + n) << 8) + (lane << 2)) = o;
                    }
            }
            // block CSE / dead-store elimination across reps
            asm volatile("" ::: "memory");
        }

        // ======== 4 recurrent steps (1 barrier each)
#pragma unroll 1
        for (int t = 0; t < 4; ++t) {
            const int step = tc*4 + t;
            const int cur = step & 1;
            const int nxt = cur ^ 1;

            __syncthreads();

            // -- issue staging loads early (hidden under MFMA)
            const bool do_stage = (t < 3) && (tc < 15);
            float4_t sv0, sv1;
            int sa0 = 0, sa1 = 0;
            if (do_stage) {
                const int tcn = tc + 1;
#pragma unroll
                for (int q = 0; q < 2; ++q) {
                    int flat = (t*2 + q)*512 + tid;
                    int w4   = flat & 15;
                    int tt   = (flat >> 4) & 3;
                    int rest = flat >> 6;
                    int c = rest % 3;
                    int b = rest / 3;
                    const float4_t v = *(const float4_t*)(
                        x + (((bbase + b)*3 + c)*4096) + (tcn*4 + tt)*64 + (w4 << 2));
                    int ai = tt*3200 + b*200 + (c << 6) + (w4 << 2);
                    if (q == 0) { sv0 = v; sa0 = ai; } else { sv1 = v; sa1 = ai; }
                }
            }

            // -- stream m=2 high-k rec fragments (coalesced; consumed at kk>=4)
            short8_t s0[4], s1[4];
#pragma unroll
            for (int k = 0; k < 4; ++k) {
                s0[k] = *(const short8_t*)(recF + (((32 + tn0)*8 + k + 4) << 9) + lane*8);
                s1[k] = *(const short8_t*)(recF + (((32 + tn1)*8 + k + 4) << 9) + lane*8);
            }

            // -- init acc from Pl (own-lane, no barrier needed)
            float4_t acc[3][2];
#pragma unroll
            for (int m = 0; m < 3; ++m)
#pragma unroll
                for (int n = 0; n < 2; ++n) {
                    const ushort4_t p = *(const ushort4_t*)(
                        Pl + ((((t*8 + wv)*3 + m)*2 + n) << 8) + (lane << 2));
                    acc[m][n] = (float4_t){b2f(p.x), b2f(p.y), b2f(p.z), b2f(p.w)};
                }

            // -- K loop: A from Hb (shared), B resident/streamed
#pragma unroll
            for (int kk = 0; kk < 4; ++kk) {
                const short8_t a = *(const short8_t*)(
                    Hb + cur*4224 + l16*264 + kk*32 + l4*8);
                acc[0][0] = __builtin_amdgcn_mfma_f32_16x16x32_bf16(a, wr01[0][0][kk], acc[0][0], 0, 0, 0);
                acc[0][1] = __builtin_amdgcn_mfma_f32_16x16x32_bf16(a, wr01[0][1][kk], acc[0][1], 0, 0, 0);
                acc[1][0] = __builtin_amdgcn_mfma_f32_16x16x32_bf16(a, wr01[1][0][kk], acc[1][0], 0, 0, 0);
                acc[1][1] = __builtin_amdgcn_mfma_f32_16x16x32_bf16(a, wr01[1][1][kk], acc[1][1], 0, 0, 0);
                acc[2][0] = __builtin_amdgcn_mfma_f32_16x16x32_bf16(a, wr2[0][kk], acc[2][0], 0, 0, 0);
                acc[2][1] = __builtin_amdgcn_mfma_f32_16x16x32_bf16(a, wr2[1][kk], acc[2][1], 0, 0, 0);
            }
#pragma unroll
            for (int kk = 4; kk < 8; ++kk) {
                const short8_t a = *(const short8_t*)(
                    Hb + cur*4224 + l16*264 + kk*32 + l4*8);
                acc[0][0] = __builtin_amdgcn_mfma_f32_16x16x32_bf16(a, wr01[0][0][kk], acc[0][0], 0, 0, 0);
                acc[0][1] = __builtin_amdgcn_mfma_f32_16x16x32_bf16(a, wr01[0][1][kk], acc[0][1], 0, 0, 0);
                acc[1][0] = __builtin_amdgcn_mfma_f32_16x16x32_bf16(a, wr01[1][0][kk], acc[1][0], 0, 0, 0);
                acc[1][1] = __builtin_amdgcn_mfma_f32_16x16x32_bf16(a, wr01[1][1][kk], acc[1][1], 0, 0, 0);
                acc[2][0] = __builtin_amdgcn_mfma_f32_16x16x32_bf16(a, s0[kk-4], acc[2][0], 0, 0, 0);
                acc[2][1] = __builtin_amdgcn_mfma_f32_16x16x32_bf16(a, s1[kk-4], acc[2][1], 0, 0, 0);
            }

            // -- finish staging writes to Al
            if (do_stage) {
                ushort4_t o;
                o.x = f2b(sv0.x); o.y = f2b(sv0.y); o.z = f2b(sv0.z); o.w = f2b(sv0.w);
                *(ushort4_t*)(Al + sa0) = o;
                o.x = f2b(sv1.x); o.y = f2b(sv1.y); o.z = f2b(sv1.z); o.w = f2b(sv1.w);
                *(ushort4_t*)(Al + sa1) = o;
            }

            // -- epilogue: C element (row=l4*4+r [batch], col [hidden])
#pragma unroll
            for (int n = 0; n < 2; ++n) {
                const int col = n ? col1 : col0;
#pragma unroll
                for (int r = 0; r < 4; ++r) {
                    const float h   = hp[n][r];
                    const float cd  = tanhf_fast(acc[0][n][r]);
                    const float g   = sigf(acc[1][n][r]);
                    const float tau = 0.5f + 1.5f * sigf(acc[2][n][r]);
                    const float hn  = tanhf_fast(h + (g*cd - h) * frcp(tau));
                    hp[n][r] = hn;
                    Hb[nxt*4224 + (l4*4 + r)*264 + col] = f2b(hn);
                }
            }
        }
    }
    __syncthreads();

    // ---- head: out[b,o] = sum_j h[b,j]*head_w[o,j] + head_b[o]
    float* hf = (float*)(smem + 12800);      // [16][257] fp32, reuse Pl space
#pragma unroll
    for (int n = 0; n < 2; ++n) {
        const int col = n ? col1 : col0;
#pragma unroll
        for (int r = 0; r < 4; ++r)
            hf[(l4*4 + r)*257 + col] = hp[n][r];
    }
    __syncthreads();
    if (tid < 160) {
        const int r = tid / 10;
        const int o = tid - r*10;
        float s = head_b[o];
        const float* wrow = head_w + o*256;
        const float* hrow = hf + r*257;
#pragma unroll 8
        for (int j = 0; j < 256; ++j) s += hrow[j] * wrow[j];
        out[bbase*10 + tid] = s;
    }
}

extern "C" void kernel_launch(void* const* d_in, const int* in_sizes, int n_in,
                              void* d_out, int out_size, void* d_ws, size_t ws_size,
                              hipStream_t stream)
{
    const float* x     = (const float*)d_in[0];
    const float* ffi_w = (const float*)d_in[1];
    const float* ffi_b = (const float*)d_in[2];
    const float* ffr_w = (const float*)d_in[3];
    const float* ff_bs = (const float*)d_in[4];
    const float* gi_w  = (const float*)d_in[5];
    const float* gi_b  = (const float*)d_in[6];
    const float* gr_w  = (const float*)d_in[7];
    const float* g_bs  = (const float*)d_in[8];
    const float* ti_w  = (const float*)d_in[9];
    const float* ti_b  = (const float*)d_in[10];
    const float* tr_w  = (const float*)d_in[11];
    const float* t_bs  = (const float*)d_in[12];
    const float* hw    = (const float*)d_in[13];
    const float* hb    = (const float*)d_in[14];

    ushort_t* ws = (ushort_t*)d_ws;   // needs 688128 bytes

    cvt_w<<<168, 256, 0, stream>>>(ffr_w, gr_w, tr_w, ffi_w, gi_w, ti_w, ws);
    ltc_fused<<<256, 512, 0, stream>>>(x, ws, ffi_b, ff_bs, gi_b, g_bs,
                                       ti_b, t_bs, hw, hb, (float*)d_out);
}